// Round 2
// baseline (752.139 us; speedup 1.0000x reference)
//
#include <hip/hip_runtime.h>

#define B_SZ   2048
#define V_SZ   50257
#define TD     2048
#define NIN    128
#define NOUT   128
#define NRECV  1628
#define KDEG   45
#define KPAD   48
#define HPL    300
#define VALSN  1632   // 1630 rounded up

typedef __bf16 bf16x8 __attribute__((ext_vector_type(8)));
typedef float  floatx16 __attribute__((ext_vector_type(16)));

__device__ __forceinline__ unsigned short f2bf(float f) {
  unsigned u = __float_as_uint(f);
  u += 0x7fffu + ((u >> 16) & 1u);
  return (unsigned short)(u >> 16);
}

// tanh(x) = 1 - 2/(exp(2x)+1); exp(2x) = exp2(x * 2*log2(e)).
__device__ __forceinline__ float tanh_fast(float v) {
  float e = __builtin_amdgcn_exp2f(v * 2.88539008177793f);
  return 1.0f - 2.0f * __builtin_amdgcn_rcpf(1.0f + e);
}

__device__ __forceinline__ bf16x8 cvt8(float4 lo, float4 hi) {
  bf16x8 d;
  d[0] = (__bf16)lo.x; d[1] = (__bf16)lo.y; d[2] = (__bf16)lo.z; d[3] = (__bf16)lo.w;
  d[4] = (__bf16)hi.x; d[5] = (__bf16)hi.y; d[6] = (__bf16)hi.z; d[7] = (__bf16)hi.w;
  return d;
}

// ---------------- prep: convert out_w/in_w, build padded (idx,w) table ------
// P0 (flat gather) removed: gemm1 now gathers token_emb directly.
#define P1 1608224
#define P2 65536
#define P4 78144
#define PREP_TOTAL (P1 + P2 + P4)               // 1751904
#define PREP_BLOCKS ((PREP_TOTAL + 255) / 256)  // 6844

__global__ __launch_bounds__(256) void prep_kernel(
    const float* __restrict__ in_w,
    const int* __restrict__ src, const float* __restrict__ rw,
    const float* __restrict__ out_w,
    unsigned short* __restrict__ inwb, unsigned short* __restrict__ outwb,
    int* __restrict__ iw) {
  int i = blockIdx.x * 256 + threadIdx.x;
  if (i < P1) {
    float4 v = ((const float4*)out_w)[i];
    ushort4 o; o.x = f2bf(v.x); o.y = f2bf(v.y); o.z = f2bf(v.z); o.w = f2bf(v.w);
    *(ushort4*)(outwb + (size_t)i * 4) = o;
    return;
  }
  i -= P1;
  if (i < P2) {
    float4 v = ((const float4*)in_w)[i];
    ushort4 o; o.x = f2bf(v.x); o.y = f2bf(v.y); o.z = f2bf(v.z); o.w = f2bf(v.w);
    *(ushort4*)(inwb + (size_t)i * 4) = o;
    return;
  }
  i -= P2;
  if (i < P4) {
    int r = i / KPAD, k = i - r * KPAD;
    int idx = 0; unsigned wb = 0;
    if (k < KDEG) {
      idx = src[r * KDEG + k];
      wb = __float_as_uint(rw[r * KDEG + k]);
    }
    iw[(size_t)i * 2] = idx;
    iw[(size_t)i * 2 + 1] = (int)wb;
  }
}

// ---------------- gemm1: x = gather(temb,ids) @ in_w^T + in_b ---------------
// 64 blocks (32 m-rows each), 4 waves = 4 n-tiles of 32. Full K=2048 per wave.
// A-fragments gathered from token_emb (fp32) and converted in-register:
// flat[m][k] = temb[ids[m][k/32]][k%32]; per token t, MFMA pair covers
// cols [32t,32t+16) and [32t+16,32t+32).
__global__ __launch_bounds__(256) void gemm1_kernel(
    const int* __restrict__ ids, const float* __restrict__ temb,
    const __bf16* __restrict__ inwb, const float* __restrict__ in_b,
    float* __restrict__ x) {
  int tid = threadIdx.x;
  int wv = tid >> 6, lane = tid & 63;
  int row = lane & 31, half = lane >> 5;
  int m0 = blockIdx.x * 32;
  int n0 = wv * 32;
  const int4* idq = (const int4*)(ids + (size_t)(m0 + row) * 64);
  const __bf16* bp = inwb + (size_t)(n0 + row) * TD + half * 8;
  floatx16 acc = (floatx16)0.0f;
  for (int t4 = 0; t4 < 16; ++t4) {
    int4 iq = idq[t4];
#pragma unroll
    for (int j = 0; j < 4; ++j) {
      int id = (j == 0) ? iq.x : (j == 1) ? iq.y : (j == 2) ? iq.z : iq.w;
      int t = t4 * 4 + j;
      const float* tp = temb + (size_t)id * 32;
      float4 a0 = *(const float4*)(tp + 8 * half);
      float4 a1 = *(const float4*)(tp + 8 * half + 4);
      float4 a2 = *(const float4*)(tp + 16 + 8 * half);
      float4 a3 = *(const float4*)(tp + 16 + 8 * half + 4);
      bf16x8 av0 = cvt8(a0, a1);
      bf16x8 av1 = cvt8(a2, a3);
      bf16x8 b0 = *(const bf16x8*)(bp + t * 32);
      bf16x8 b1 = *(const bf16x8*)(bp + t * 32 + 16);
      acc = __builtin_amdgcn_mfma_f32_32x32x16_bf16(av0, b0, acc, 0, 0, 0);
      acc = __builtin_amdgcn_mfma_f32_32x32x16_bf16(av1, b1, acc, 0, 0, 0);
    }
  }
  int col = n0 + row;
  float bias = in_b[col];
#pragma unroll
  for (int r = 0; r < 16; ++r) {
    int mrow = (r & 3) + 8 * (r >> 2) + 4 * half;
    x[(size_t)(m0 + mrow) * NIN + col] = acc[r] + bias;
  }
}

// ---------------- rwnn: sparse DAG forward, 8 batch elems / block ------------
// 512 threads: 4 threads per node-row (batch-pairs, float2), 8 waves/CU.
__global__ __launch_bounds__(512) void rwnn_kernel(
    const float* __restrict__ x, const int* __restrict__ iw,
    unsigned short* __restrict__ hb) {
  __shared__ float vals[VALSN * 8];   // [node][batch8], 52224 B
  int tid = threadIdx.x;
  int b0 = blockIdx.x * 8;
  {
    int p = tid & 7, n = tid >> 3;           // n in 0..63
    vals[n * 8 + p] = x[(b0 + p) * NIN + n];
    vals[(n + 64) * 8 + p] = x[(b0 + p) * NIN + n + 64];
    if (tid < 16) vals[(NIN + (tid >> 3)) * 8 + (tid & 7)] = 1.0f;
  }
  __syncthreads();
  int g = tid >> 2;          // 0..127 node group
  int pq = (tid & 3) * 2;    // batch pair offset: 0,2,4,6
  int base = NIN + 2;        // 130
  int off = 0;
  for (int layer = 0; layer < 5; ++layer) {
    for (int r = g; r < HPL; r += 128) {
      const int4* q4 = (const int4*)(iw) + (size_t)(off + r) * (KPAD / 2);
      float s0 = 0.f, s1 = 0.f;
#pragma unroll
      for (int k4 = 0; k4 < KPAD / 2; ++k4) {
        int4 q = q4[k4];
        float2 v0 = *(const float2*)(&vals[q.x * 8 + pq]);
        float w0 = __int_as_float(q.y);
        s0 += v0.x * w0; s1 += v0.y * w0;
        float2 v1 = *(const float2*)(&vals[q.z * 8 + pq]);
        float w1 = __int_as_float(q.w);
        s0 += v1.x * w1; s1 += v1.y * w1;
      }
      float2 o; o.x = tanh_fast(s0); o.y = tanh_fast(s1);
      *(float2*)(&vals[(base + r) * 8 + pq]) = o;
    }
    __syncthreads();
    off += HPL; base += HPL;
  }
  {
    int r = g;
    const int4* q4 = (const int4*)(iw) + (size_t)(off + r) * (KPAD / 2);
    float s0 = 0.f, s1 = 0.f;
#pragma unroll
    for (int k4 = 0; k4 < KPAD / 2; ++k4) {
      int4 q = q4[k4];
      float2 v0 = *(const float2*)(&vals[q.x * 8 + pq]);
      float w0 = __int_as_float(q.y);
      s0 += v0.x * w0; s1 += v0.y * w0;
      float2 v1 = *(const float2*)(&vals[q.z * 8 + pq]);
      float w1 = __int_as_float(q.w);
      s0 += v1.x * w1; s1 += v1.y * w1;
    }
    hb[(b0 + pq + 0) * NOUT + r] = f2bf(tanh_fast(s0));
    hb[(b0 + pq + 1) * NOUT + r] = f2bf(tanh_fast(s1));
  }
}

// ---------------- gemm3: logits = h @ out_w^T + out_b -----------------------
// 128m x 128v blocks: B-fragments register-resident across 4 m-tiles (4x less
// out_w L2 traffic); non-temporal stores keep the 412 MB stream out of L2.
__global__ __launch_bounds__(256) void gemm3_kernel(
    const __bf16* __restrict__ h, const __bf16* __restrict__ wv,
    const float* __restrict__ out_b, float* __restrict__ out) {
  int tid = threadIdx.x;
  int wvid = tid >> 6, lane = tid & 63;
  int row = lane & 31, half = lane >> 5;
  int m0 = blockIdx.x * 128;
  int v0 = blockIdx.y * 128 + wvid * 32;
  int vr = v0 + row;
  int vc = vr < V_SZ ? vr : V_SZ - 1;
  const __bf16* bp = wv + (size_t)vc * NOUT + half * 8;
  bf16x8 bfrag[8];
#pragma unroll
  for (int s = 0; s < 8; ++s) bfrag[s] = *(const bf16x8*)(bp + s * 16);
  float bias = (vr < V_SZ) ? out_b[vr] : 0.f;
#pragma unroll
  for (int mt = 0; mt < 4; ++mt) {
    const __bf16* ap = h + (size_t)(m0 + mt * 32 + row) * NOUT + half * 8;
    floatx16 acc = (floatx16)0.0f;
#pragma unroll
    for (int s = 0; s < 8; ++s) {
      bf16x8 a = *(const bf16x8*)(ap + s * 16);
      acc = __builtin_amdgcn_mfma_f32_32x32x16_bf16(a, bfrag[s], acc, 0, 0, 0);
    }
    if (vr < V_SZ) {
#pragma unroll
      for (int r = 0; r < 16; ++r) {
        int mrow = (r & 3) + 8 * (r >> 2) + 4 * half;
        __builtin_nontemporal_store(acc[r] + bias,
            &out[(size_t)(m0 + mt * 32 + mrow) * V_SZ + vr]);
      }
    }
  }
}

// ---------------- launch -----------------------------------------------------
extern "C" void kernel_launch(void* const* d_in, const int* in_sizes, int n_in,
                              void* d_out, int out_size, void* d_ws, size_t ws_size,
                              hipStream_t stream) {
  const int*   ids   = (const int*)d_in[0];
  const float* temb  = (const float*)d_in[1];
  const float* in_w  = (const float*)d_in[2];
  const float* in_b  = (const float*)d_in[3];
  const int*   src   = (const int*)d_in[4];
  const float* rw    = (const float*)d_in[5];
  const float* out_w = (const float*)d_in[6];
  const float* out_b = (const float*)d_in[7];
  float* out = (float*)d_out;

  char* ws = (char*)d_ws;
  unsigned short* inwb  = (unsigned short*)(ws + 8388608);
  unsigned short* outwb = (unsigned short*)(ws + 8912896);
  float*          x     = (float*)(ws + 21778688);
  unsigned short* hb    = (unsigned short*)(ws + 22827264);
  int*            iw    = (int*)(ws + 23351552);

  prep_kernel<<<PREP_BLOCKS, 256, 0, stream>>>(in_w, src, rw, out_w,
                                               inwb, outwb, iw);
  gemm1_kernel<<<64, 256, 0, stream>>>(ids, temb, (const __bf16*)inwb, in_b, x);
  rwnn_kernel<<<256, 512, 0, stream>>>(x, iw, hb);
  gemm3_kernel<<<dim3(16, 393), 256, 0, stream>>>((const __bf16*)hb,
                                                  (const __bf16*)outwb, out_b, out);
}

// Round 3
// 630.874 us; speedup vs baseline: 1.1922x; 1.1922x over previous
//
#include <hip/hip_runtime.h>

#define B_SZ   2048
#define V_SZ   50257
#define TD     2048
#define NIN    128
#define NOUT   128
#define NRECV  1628
#define KDEG   45
#define KPAD   48
#define HPL    300
#define VALSN  1632   // 1630 rounded up

typedef __bf16 bf16x8 __attribute__((ext_vector_type(8)));
typedef float  floatx16 __attribute__((ext_vector_type(16)));

__device__ __forceinline__ unsigned short f2bf(float f) {
  unsigned u = __float_as_uint(f);
  u += 0x7fffu + ((u >> 16) & 1u);
  return (unsigned short)(u >> 16);
}

// tanh(x) = 1 - 2/(exp(2x)+1); exp(2x) = exp2(x * 2*log2(e)).
__device__ __forceinline__ float tanh_fast(float v) {
  float e = __builtin_amdgcn_exp2f(v * 2.88539008177793f);
  return 1.0f - 2.0f * __builtin_amdgcn_rcpf(1.0f + e);
}

__device__ __forceinline__ bf16x8 cvt8(float4 lo, float4 hi) {
  bf16x8 d;
  d[0] = (__bf16)lo.x; d[1] = (__bf16)lo.y; d[2] = (__bf16)lo.z; d[3] = (__bf16)lo.w;
  d[4] = (__bf16)hi.x; d[5] = (__bf16)hi.y; d[6] = (__bf16)hi.z; d[7] = (__bf16)hi.w;
  return d;
}

// ---------------- prep: convert out_w/in_w, build padded (idx,w) table ------
#define P1 1608224
#define P2 65536
#define P4 78144
#define PREP_TOTAL (P1 + P2 + P4)               // 1751904
#define PREP_BLOCKS ((PREP_TOTAL + 255) / 256)  // 6844

__global__ __launch_bounds__(256) void prep_kernel(
    const float* __restrict__ in_w,
    const int* __restrict__ src, const float* __restrict__ rw,
    const float* __restrict__ out_w,
    unsigned short* __restrict__ inwb, unsigned short* __restrict__ outwb,
    int* __restrict__ iw) {
  int i = blockIdx.x * 256 + threadIdx.x;
  if (i < P1) {
    float4 v = ((const float4*)out_w)[i];
    ushort4 o; o.x = f2bf(v.x); o.y = f2bf(v.y); o.z = f2bf(v.z); o.w = f2bf(v.w);
    *(ushort4*)(outwb + (size_t)i * 4) = o;
    return;
  }
  i -= P1;
  if (i < P2) {
    float4 v = ((const float4*)in_w)[i];
    ushort4 o; o.x = f2bf(v.x); o.y = f2bf(v.y); o.z = f2bf(v.z); o.w = f2bf(v.w);
    *(ushort4*)(inwb + (size_t)i * 4) = o;
    return;
  }
  i -= P2;
  if (i < P4) {
    int r = i / KPAD, k = i - r * KPAD;
    int idx = 0; unsigned wb = 0;
    if (k < KDEG) {
      idx = src[r * KDEG + k];
      wb = __float_as_uint(rw[r * KDEG + k]);
    }
    iw[(size_t)i * 2] = idx;
    iw[(size_t)i * 2 + 1] = (int)wb;
  }
}

// ---------------- gemm1: x = gather(temb,ids) @ in_w^T + in_b ---------------
__global__ __launch_bounds__(256) void gemm1_kernel(
    const int* __restrict__ ids, const float* __restrict__ temb,
    const __bf16* __restrict__ inwb, const float* __restrict__ in_b,
    float* __restrict__ x) {
  int tid = threadIdx.x;
  int wv = tid >> 6, lane = tid & 63;
  int row = lane & 31, half = lane >> 5;
  int m0 = blockIdx.x * 32;
  int n0 = wv * 32;
  const int4* idq = (const int4*)(ids + (size_t)(m0 + row) * 64);
  const __bf16* bp = inwb + (size_t)(n0 + row) * TD + half * 8;
  floatx16 acc = (floatx16)0.0f;
  for (int t4 = 0; t4 < 16; ++t4) {
    int4 iq = idq[t4];
#pragma unroll
    for (int j = 0; j < 4; ++j) {
      int id = (j == 0) ? iq.x : (j == 1) ? iq.y : (j == 2) ? iq.z : iq.w;
      int t = t4 * 4 + j;
      const float* tp = temb + (size_t)id * 32;
      float4 a0 = *(const float4*)(tp + 8 * half);
      float4 a1 = *(const float4*)(tp + 8 * half + 4);
      float4 a2 = *(const float4*)(tp + 16 + 8 * half);
      float4 a3 = *(const float4*)(tp + 16 + 8 * half + 4);
      bf16x8 av0 = cvt8(a0, a1);
      bf16x8 av1 = cvt8(a2, a3);
      bf16x8 b0 = *(const bf16x8*)(bp + t * 32);
      bf16x8 b1 = *(const bf16x8*)(bp + t * 32 + 16);
      acc = __builtin_amdgcn_mfma_f32_32x32x16_bf16(av0, b0, acc, 0, 0, 0);
      acc = __builtin_amdgcn_mfma_f32_32x32x16_bf16(av1, b1, acc, 0, 0, 0);
    }
  }
  int col = n0 + row;
  float bias = in_b[col];
#pragma unroll
  for (int r = 0; r < 16; ++r) {
    int mrow = (r & 3) + 8 * (r >> 2) + 4 * half;
    x[(size_t)(m0 + mrow) * NIN + col] = acc[r] + bias;
  }
}

// ---------------- rwnn: sparse DAG forward, 8 batch elems / block ------------
__global__ __launch_bounds__(512) void rwnn_kernel(
    const float* __restrict__ x, const int* __restrict__ iw,
    unsigned short* __restrict__ hb) {
  __shared__ float vals[VALSN * 8];   // [node][batch8], 52224 B
  int tid = threadIdx.x;
  int b0 = blockIdx.x * 8;
  {
    int p = tid & 7, n = tid >> 3;           // n in 0..63
    vals[n * 8 + p] = x[(b0 + p) * NIN + n];
    vals[(n + 64) * 8 + p] = x[(b0 + p) * NIN + n + 64];
    if (tid < 16) vals[(NIN + (tid >> 3)) * 8 + (tid & 7)] = 1.0f;
  }
  __syncthreads();
  int g = tid >> 2;          // 0..127 node group
  int pq = (tid & 3) * 2;    // batch pair offset: 0,2,4,6
  int base = NIN + 2;        // 130
  int off = 0;
  for (int layer = 0; layer < 5; ++layer) {
    for (int r = g; r < HPL; r += 128) {
      const int4* q4 = (const int4*)(iw) + (size_t)(off + r) * (KPAD / 2);
      float s0 = 0.f, s1 = 0.f;
#pragma unroll
      for (int k4 = 0; k4 < KPAD / 2; ++k4) {
        int4 q = q4[k4];
        float2 v0 = *(const float2*)(&vals[q.x * 8 + pq]);
        float w0 = __int_as_float(q.y);
        s0 += v0.x * w0; s1 += v0.y * w0;
        float2 v1 = *(const float2*)(&vals[q.z * 8 + pq]);
        float w1 = __int_as_float(q.w);
        s0 += v1.x * w1; s1 += v1.y * w1;
      }
      float2 o; o.x = tanh_fast(s0); o.y = tanh_fast(s1);
      *(float2*)(&vals[(base + r) * 8 + pq]) = o;
    }
    __syncthreads();
    off += HPL; base += HPL;
  }
  {
    int r = g;
    const int4* q4 = (const int4*)(iw) + (size_t)(off + r) * (KPAD / 2);
    float s0 = 0.f, s1 = 0.f;
#pragma unroll
    for (int k4 = 0; k4 < KPAD / 2; ++k4) {
      int4 q = q4[k4];
      float2 v0 = *(const float2*)(&vals[q.x * 8 + pq]);
      float w0 = __int_as_float(q.y);
      s0 += v0.x * w0; s1 += v0.y * w0;
      float2 v1 = *(const float2*)(&vals[q.z * 8 + pq]);
      float w1 = __int_as_float(q.w);
      s0 += v1.x * w1; s1 += v1.y * w1;
    }
    hb[(b0 + pq + 0) * NOUT + r] = f2bf(tanh_fast(s0));
    hb[(b0 + pq + 1) * NOUT + r] = f2bf(tanh_fast(s1));
  }
}

// ---------------- gemm3: logits = h @ out_w^T + out_b -----------------------
// 128m x 128v blocks, B-fragments register-resident. Regular (cached) stores:
// rows are only 4B-aligned (V*4 % 128 == 4), so L2 write-back must merge the
// straddling 128B chunks — NT stores defeated that (WRITE_SIZE 546 vs 412 MB).
// blockIdx.x walks v-tiles: consecutive blocks write adjacent v-ranges.
__global__ __launch_bounds__(256) void gemm3_kernel(
    const __bf16* __restrict__ h, const __bf16* __restrict__ wv,
    const float* __restrict__ out_b, float* __restrict__ out) {
  int tid = threadIdx.x;
  int wvid = tid >> 6, lane = tid & 63;
  int row = lane & 31, half = lane >> 5;
  int m0 = blockIdx.y * 128;
  int v0 = blockIdx.x * 128 + wvid * 32;
  int vr = v0 + row;
  int vc = vr < V_SZ ? vr : V_SZ - 1;
  const __bf16* bp = wv + (size_t)vc * NOUT + half * 8;
  bf16x8 bfrag[8];
#pragma unroll
  for (int s = 0; s < 8; ++s) bfrag[s] = *(const bf16x8*)(bp + s * 16);
  float bias = (vr < V_SZ) ? out_b[vr] : 0.f;
#pragma unroll
  for (int mt = 0; mt < 4; ++mt) {
    const __bf16* ap = h + (size_t)(m0 + mt * 32 + row) * NOUT + half * 8;
    floatx16 acc = (floatx16)0.0f;
#pragma unroll
    for (int s = 0; s < 8; ++s) {
      bf16x8 a = *(const bf16x8*)(ap + s * 16);
      acc = __builtin_amdgcn_mfma_f32_32x32x16_bf16(a, bfrag[s], acc, 0, 0, 0);
    }
    if (vr < V_SZ) {
#pragma unroll
      for (int r = 0; r < 16; ++r) {
        int mrow = (r & 3) + 8 * (r >> 2) + 4 * half;
        out[(size_t)(m0 + mt * 32 + mrow) * V_SZ + vr] = acc[r] + bias;
      }
    }
  }
}

// ---------------- launch -----------------------------------------------------
extern "C" void kernel_launch(void* const* d_in, const int* in_sizes, int n_in,
                              void* d_out, int out_size, void* d_ws, size_t ws_size,
                              hipStream_t stream) {
  const int*   ids   = (const int*)d_in[0];
  const float* temb  = (const float*)d_in[1];
  const float* in_w  = (const float*)d_in[2];
  const float* in_b  = (const float*)d_in[3];
  const int*   src   = (const int*)d_in[4];
  const float* rw    = (const float*)d_in[5];
  const float* out_w = (const float*)d_in[6];
  const float* out_b = (const float*)d_in[7];
  float* out = (float*)d_out;

  char* ws = (char*)d_ws;
  unsigned short* inwb  = (unsigned short*)(ws + 8388608);
  unsigned short* outwb = (unsigned short*)(ws + 8912896);
  float*          x     = (float*)(ws + 21778688);
  unsigned short* hb    = (unsigned short*)(ws + 22827264);
  int*            iw    = (int*)(ws + 23351552);

  prep_kernel<<<PREP_BLOCKS, 256, 0, stream>>>(in_w, src, rw, out_w,
                                               inwb, outwb, iw);
  gemm1_kernel<<<64, 256, 0, stream>>>(ids, temb, (const __bf16*)inwb, in_b, x);
  rwnn_kernel<<<256, 512, 0, stream>>>(x, iw, hb);
  gemm3_kernel<<<dim3(393, 16), 256, 0, stream>>>((const __bf16*)hb,
                                                  (const __bf16*)outwb, out_b, out);
}